// Round 9
// baseline (389.715 us; speedup 1.0000x reference)
//
#include <hip/hip_runtime.h>
#include <math.h>

typedef __attribute__((ext_vector_type(8)))  short  short8;    // 8 bf16
typedef __attribute__((ext_vector_type(4)))  short  svec4;     // 4 bf16 (b64)
typedef __attribute__((ext_vector_type(4)))  float  floatx4;
typedef __attribute__((ext_vector_type(16))) float  floatx16;
typedef __attribute__((ext_vector_type(2)))  unsigned uintx2;

__device__ __forceinline__ short bf16rne(float f) {
    unsigned u = __float_as_uint(f);
    unsigned r = (u + 0x7FFFu + ((u >> 16) & 1u)) >> 16;
    return (short)r;
}
__device__ __forceinline__ unsigned pk2(float a, float b) {
#if __has_builtin(__builtin_amdgcn_cvt_pk_bf16_f32)
    auto t = __builtin_amdgcn_cvt_pk_bf16_f32(a, b);
    unsigned u; __builtin_memcpy(&u, &t, 4); return u;
#else
    return (unsigned)(unsigned short)bf16rne(a) |
           ((unsigned)(unsigned short)bf16rne(b) << 16);
#endif
}

// ws: [0,8192) feat_sum; frags at 8192: 11 x 64 x 16B (W1a, W1b, B2[0..8]);
// conv1 C-init bias at +11264 (64 x float4); conv2 bias at +12288 (64 x f32)
#define WS_FRAG_OFF  8192
#define WS_BIAS1_OFF (WS_FRAG_OFF + 11 * 64 * 16)
#define WS_BIAS2_OFF (WS_BIAS1_OFF + 64 * 16)

#define PLANE_B 9792             // bytes per h1 ic-half plane (34*18 px * 16 B)

// ---------------------------------------------------------------------------
// Setup: build MFMA weight fragments + bias tables, zero feat & out-load.
// conv1 K-map: k = p*4 + c for positions p=0..7 (MFMA #1); position 8 in
// MFMA #2 at k=c (rest zero). c=3 is a zero pad channel.
// ---------------------------------------------------------------------------
__global__ __launch_bounds__(256) void build_frags_kernel(
    const float* __restrict__ w1,   // (16,3,9) = [oc][c][p]
    const float* __restrict__ b1,   // (16,)
    const float* __restrict__ w2,   // (32,16,9)
    const float* __restrict__ b2,   // (32,)
    void* __restrict__ ws,
    float* __restrict__ out)        // gates(4096) + load(64)
{
    const int t = threadIdx.x;
    float* feat = (float*)ws;
    for (int i = t; i < 2048; i += 256) feat[i] = 0.0f;
    if (t >= 64 && t < 128) out[4096 + (t - 64)] = 0.0f;

    if (t < 64) {
        const int lane = t;
        const int q = lane >> 4, ml = lane & 15;
        const int n32 = lane & 31, half = lane >> 5;
        short8* F = (short8*)((char*)ws + WS_FRAG_OFF);

        // W1a (A-operand, 16x16x32): A[m=ml=oc][k=q*8+j], p=q*2+(j>>2), c=j&3
        short8 W1a;
#pragma unroll
        for (int j = 0; j < 8; ++j) {
            int p = q * 2 + (j >> 2), c = j & 3;
            W1a[j] = (c < 3) ? bf16rne(w1[ml * 27 + c * 9 + p]) : (short)0;
        }
        F[0 * 64 + lane] = W1a;

        // W1b: position 8 only, k=c (q==0, j<3); zero elsewhere
        short8 W1b;
#pragma unroll
        for (int j = 0; j < 8; ++j) {
            W1b[j] = (q == 0 && j < 3) ? bf16rne(w1[ml * 27 + j * 9 + 8])
                                       : (short)0;
        }
        F[1 * 64 + lane] = W1b;

        // conv2 B-frags (32x32x16): B[k=half*8+j=ic][n=n32=oc] = w2[(oc*16+ic)*9+s]
#pragma unroll
        for (int s = 0; s < 9; ++s) {
            short8 Bs;
#pragma unroll
            for (int j = 0; j < 8; ++j) {
                int ic = half * 8 + j;
                Bs[j] = bf16rne(w2[(n32 * 16 + ic) * 9 + s]);
            }
            F[(2 + s) * 64 + lane] = Bs;
        }
        floatx4 bv;
#pragma unroll
        for (int r = 0; r < 4; ++r) bv[r] = b1[q * 4 + r];
        ((floatx4*)((char*)ws + WS_BIAS1_OFF))[lane] = bv;
        ((float*)((char*)ws + WS_BIAS2_OFF))[lane] = b2[n32];
    }
}

// one conv1 micro-tile: 3 b64 gathers, 2 MFMA, relu, pack, b64 store to the
// lane's ic-half plane position (wptr already includes plane + (q&1)*8).
__device__ __forceinline__ void conv1_tile(
    char* __restrict__ wptr, const char* __restrict__ inb,
    const int* lcB, int gbyte, int wbyte, bool valid, bool wmask,
    short8 W1a, short8 W1b, floatx4 biasv)
{
    svec4 r0 = *(const svec4*)(inb + gbyte + lcB[0]);
    svec4 r1 = *(const svec4*)(inb + gbyte + lcB[1]);
    svec4 r2 = *(const svec4*)(inb + gbyte + lcB[2]);
    short8 Bx, By;
    Bx[0]=r0[0]; Bx[1]=r0[1]; Bx[2]=r0[2]; Bx[3]=r0[3];
    Bx[4]=r1[0]; Bx[5]=r1[1]; Bx[6]=r1[2]; Bx[7]=r1[3];
    By[0]=r2[0]; By[1]=r2[1]; By[2]=r2[2]; By[3]=r2[3];
    By[4]=r2[0]; By[5]=r2[1]; By[6]=r2[2]; By[7]=r2[3];   // W1b=0 for k>=4
    floatx4 acc = biasv;
    acc = __builtin_amdgcn_mfma_f32_16x16x32_bf16(W1a, Bx, acc, 0, 0, 0);
    acc = __builtin_amdgcn_mfma_f32_16x16x32_bf16(W1b, By, acc, 0, 0, 0);
    float v0 = fmaxf(acc[0], 0.f), v1 = fmaxf(acc[1], 0.f);
    float v2 = fmaxf(acc[2], 0.f), v3 = fmaxf(acc[3], 0.f);
    if (!valid) { v0 = 0.f; v1 = 0.f; v2 = 0.f; v3 = 0.f; }
    if (wmask) {
        uintx2 w; w.x = pk2(v0, v1); w.y = pk2(v2, v3);
        *(uintx2*)(wptr + wbyte) = w;
    }
}

// ---------------------------------------------------------------------------
// Kernel A: 32(rows)x16(cols) output tile per block, 6 blocks/CU (25.9 KB
// LDS). conv1+relu (2x 16x16x32 MFMA) -> conv2+relu (32x32x16 MFMA, 9-shift,
// sliding A-window) -> spatial sum -> atomicAdd feat_sum[B][32].
// 256 threads = 4 waves, grid (16,8,64).
// ---------------------------------------------------------------------------
__global__ __launch_bounds__(256, 6) void conv_feat_kernel(
    const float* __restrict__ x,      // (64,3,256,256)
    const void*  __restrict__ ws_ro,
    float* __restrict__ feat_sum)     // (64,32)
{
    __shared__ short s_in4[36 * 20 * 4];   // bf16 [r][col][c pad4] (5760 B)
    __shared__ short s_h1[2 * 4896];       // two ic-half planes 34x18 px (19584 B)
    __shared__ float s_part[4][32];

    const int t    = threadIdx.x;
    const int lane = t & 63, wv = t >> 6;
    const int q    = lane >> 4, ml = lane & 15;
    const int n32  = lane & 31, half = lane >> 5;
    const int tx = blockIdx.x, ty = blockIdx.y, b = blockIdx.z;
    const bool border = (tx == 0) | (tx == 15) | (ty == 0) | (ty == 7);

    // ---- weight fragments / biases ----
    const short8* F = (const short8*)((const char*)ws_ro + WS_FRAG_OFF);
    short8 W1a = F[0 * 64 + lane];
    short8 W1b = F[1 * 64 + lane];
    short8 B2[9];
#pragma unroll
    for (int s = 0; s < 9; ++s) B2[s] = F[(2 + s) * 64 + lane];
    floatx4 biasv = ((const floatx4*)((const char*)ws_ro + WS_BIAS1_OFF))[lane];
    float   b2v   = ((const float*)((const char*)ws_ro + WS_BIAS2_OFF))[lane];

    // conv1 gather byte offsets (row stride 20 px * 8 B): positions q*2,q*2+1,8
    int lcB[3];
    {
        int p0 = q * 2, p1 = q * 2 + 1;
        lcB[0] = ((p0 / 3) * 20 + p0 % 3) * 8;
        lcB[1] = ((p1 / 3) * 20 + p1 % 3) * 8;
        lcB[2] = (2 * 20 + 2) * 8;
    }

    // ---- stage input tile as bf16 [r][col][4] (halo 2): 36 rows x 20 cols ----
    const int gy0 = ty * 32 - 2, gx0 = tx * 16 - 2;
    const float* xb = x + (size_t)b * 3 * 65536;
    if (!border) {
        for (int i = t; i < 720; i += 256) {
            int r = i / 20, c = i - r * 20;
            const float* p = xb + (gy0 + r) * 256 + gx0 + c;
            float v0 = p[0], v1 = p[65536], v2 = p[131072];
            uintx2 w; w.x = pk2(v0, v1); w.y = pk2(v2, 0.f);
            *(uintx2*)&s_in4[i * 4] = w;
        }
    } else {
        for (int i = t; i < 720; i += 256) {
            int r = i / 20, c = i - r * 20;
            int gy = gy0 + r, gx = gx0 + c;
            float v0 = 0.f, v1 = 0.f, v2 = 0.f;
            if ((unsigned)gy < 256u && (unsigned)gx < 256u) {
                const float* p = xb + gy * 256 + gx;
                v0 = p[0]; v1 = p[65536]; v2 = p[131072];
            }
            uintx2 w; w.x = pk2(v0, v1); w.y = pk2(v2, 0.f);
            *(uintx2*)&s_in4[i * 4] = w;
        }
    }
    __syncthreads();

    // ---- conv1 over 34x18 h1: 34 row-units + 4 col-units + corner ----
    char* wptr = (char*)s_h1 + (q >> 1) * PLANE_B + (q & 1) * 8;
    const char* inb = (const char*)s_in4;
    const int mlb = ml * 8;
    if (!border) {
#pragma unroll
        for (int i = 0; i < 8; ++i) {
            int u = wv * 8 + i;          // rows 0..31, cols 0..15
            conv1_tile(wptr, inb, lcB, u * 160 + mlb,
                       (u * 18 + ml) * 16, true, true, W1a, W1b, biasv);
        }
        if (wv < 2) {                    // rows 32,33
            int u = 32 + wv;
            conv1_tile(wptr, inb, lcB, u * 160 + mlb,
                       (u * 18 + ml) * 16, true, true, W1a, W1b, biasv);
        }
        {   // col unit: rows wv*8+(ml>>1), col 16+(ml&1)
            int rr = wv * 8 + (ml >> 1), cc = 16 + (ml & 1);
            conv1_tile(wptr, inb, lcB, rr * 160 + cc * 8,
                       (rr * 18 + cc) * 16, true, true, W1a, W1b, biasv);
        }
        if (wv == 2) {   // corner 4 px: rows 32-33 x cols 16-17
            int ml2 = ml & 3;
            int iy = 32 + (ml2 >> 1), ix = 16 + (ml2 & 1);
            conv1_tile(wptr, inb, lcB, iy * 160 + ix * 8,
                       (iy * 18 + ix) * 16, true, ml < 4, W1a, W1b, biasv);
        }
    } else {
        const bool gxOK = (unsigned)(tx * 16 - 1 + ml) < 256u;
#pragma unroll
        for (int i = 0; i < 8; ++i) {
            int u = wv * 8 + i;
            bool ok = ((unsigned)(ty * 32 - 1 + u) < 256u) & gxOK;
            conv1_tile(wptr, inb, lcB, u * 160 + mlb,
                       (u * 18 + ml) * 16, ok, true, W1a, W1b, biasv);
        }
        if (wv < 2) {
            int u = 32 + wv;
            bool ok = ((unsigned)(ty * 32 - 1 + u) < 256u) & gxOK;
            conv1_tile(wptr, inb, lcB, u * 160 + mlb,
                       (u * 18 + ml) * 16, ok, true, W1a, W1b, biasv);
        }
        {
            int rr = wv * 8 + (ml >> 1), cc = 16 + (ml & 1);
            bool ok = ((unsigned)(ty * 32 - 1 + rr) < 256u) &
                      ((unsigned)(tx * 16 - 1 + cc) < 256u);
            conv1_tile(wptr, inb, lcB, rr * 160 + cc * 8,
                       (rr * 18 + cc) * 16, ok, true, W1a, W1b, biasv);
        }
        if (wv == 2) {
            int ml2 = ml & 3;
            int iy = 32 + (ml2 >> 1), ix = 16 + (ml2 & 1);
            bool ok = ((unsigned)(ty * 32 - 1 + iy) < 256u) &
                      ((unsigned)(tx * 16 - 1 + ix) < 256u);
            conv1_tile(wptr, inb, lcB, iy * 160 + ix * 8,
                       (iy * 18 + ix) * 16, ok, ml < 4, W1a, W1b, biasv);
        }
    }
    __syncthreads();

    // ---- conv2: wave = 4 vertically-chained 32-px tiles (2 rows x 16 cols),
    //      rows wv*8..wv*8+7, sliding 3x3 A-frag window ----
    float part = 0.0f;
    {
        const int prow0 = n32 >> 4, pcol = n32 & 15;
        const char* pl = (const char*)s_h1 + half * PLANE_B;
        int pb = ((wv * 8 + prow0) * 18 + pcol) * 16;
        short8 Af[3][3];
#pragma unroll
        for (int ky = 0; ky < 3; ++ky)
#pragma unroll
            for (int kx = 0; kx < 3; ++kx)
                Af[ky][kx] = *(const short8*)(pl + pb + (ky * 18 + kx) * 16);
#pragma unroll
        for (int it = 0; it < 4; ++it) {
            const int rb = (2 * it) % 3;
            floatx16 acc;
#pragma unroll
            for (int r = 0; r < 16; ++r) acc[r] = b2v;
#pragma unroll
            for (int s = 0; s < 9; ++s) {
                const int ky = s / 3, kx = s % 3;
                acc = __builtin_amdgcn_mfma_f32_32x32x16_bf16(
                        Af[(rb + ky) % 3][kx], B2[s], acc, 0, 0, 0);
            }
#pragma unroll
            for (int r = 0; r < 16; ++r) part += fmaxf(acc[r], 0.0f);
            if (it < 3) {
                pb += 576;   // advance 2 h1 rows (2*18*16 B)
#pragma unroll
                for (int kx = 0; kx < 3; ++kx) {
                    Af[rb][kx] =
                        *(const short8*)(pl + pb + (18 + kx) * 16);
                    Af[(rb + 1) % 3][kx] =
                        *(const short8*)(pl + pb + (36 + kx) * 16);
                }
            }
        }
    }
    part += __shfl_xor(part, 32);
    if (lane < 32) s_part[wv][n32] = part;
    __syncthreads();
    if (t < 32) {
        float ssum = s_part[0][t] + s_part[1][t] + s_part[2][t] + s_part[3][t];
        atomicAdd(feat_sum + b * 32 + t, ssum);
    }
}

// ---------------------------------------------------------------------------
// Kernel B: gating. One block per batch row, 64 threads (= experts, 1 wave).
// ---------------------------------------------------------------------------
__global__ __launch_bounds__(64) void router_gate_kernel(
    const int* __restrict__ task_id,
    const float* __restrict__ noise,
    const float* __restrict__ mlp_w1,
    const float* __restrict__ mlp_b1,
    const float* __restrict__ mlp_w2,
    const float* __restrict__ mlp_b2,
    const float* __restrict__ deg_w,
    const float* __restrict__ deg_b,
    const float* __restrict__ keys,
    const float* __restrict__ gate_w,
    const float* __restrict__ gate_b,
    const float* __restrict__ noise_w,
    const float* __restrict__ noise_b,
    const float* __restrict__ feat_sum,
    float* __restrict__ out)
{
    const int b = blockIdx.x;
    const int e = threadIdx.x;

    __shared__ float s_te[32];
    __shared__ float s_comb[32];
    __shared__ float s_ew[64];

    if (e < 32) {
        float tf = (float)task_id[b];
        s_te[e] = fmaxf(tf * mlp_w1[e] + mlp_b1[e], 0.0f);
    }
    __syncthreads();
    if (e < 32) {
        float acc = mlp_b2[e];
        for (int k = 0; k < 32; ++k) acc += s_te[k] * mlp_w2[k * 32 + e];
        float dacc = deg_b[e];
        for (int c = 0; c < 32; ++c)
            dacc += (feat_sum[b * 32 + c] * (1.0f / 65536.0f)) * deg_w[c * 32 + e];
        s_comb[e] = acc + 0.2f * dacc;  // ALPHA = 0.8
    }
    __syncthreads();

    float s = 0.0f;
    for (int d = 0; d < 32; ++d) s += s_comb[d] * keys[e * 32 + d];
    s *= 0.17677669529663687f;  // 1/sqrt(32)

    float m = s;
    for (int off = 32; off; off >>= 1) m = fmaxf(m, __shfl_xor(m, off));
    float p = expf(s - m);
    float sum = p;
    for (int off = 32; off; off >>= 1) sum += __shfl_xor(sum, off);
    float w = p / sum;
    s_ew[e] = w;
    __syncthreads();

    float cl = gate_b[e], nz = noise_b[e];
    for (int k = 0; k < 64; ++k) {
        float ewk = s_ew[k];
        cl += ewk * gate_w[k * 64 + e];
        nz += ewk * noise_w[k * 64 + e];
    }
    float sp = (nz > 20.0f) ? nz : log1pf(expf(nz));
    float logit = cl + noise[b * 64 + e] * (sp + 0.01f);

    float v0 = logit; int i0 = e;
    for (int off = 32; off; off >>= 1) {
        float ov = __shfl_xor(v0, off);
        int   oi = __shfl_xor(i0, off);
        if (ov > v0 || (ov == v0 && oi < i0)) { v0 = ov; i0 = oi; }
    }
    float v1 = (e == i0) ? -INFINITY : logit; int i1 = e;
    for (int off = 32; off; off >>= 1) {
        float ov = __shfl_xor(v1, off);
        int   oi = __shfl_xor(i1, off);
        if (ov > v1 || (ov == v1 && oi < i1)) { v1 = ov; i1 = oi; }
    }

    float e1 = expf(v1 - v0);
    float g0 = 1.0f / (1.0f + e1);
    float g1 = e1 / (1.0f + e1);

    float g = (e == i0) ? g0 : (e == i1) ? g1 : 0.0f;
    out[b * 64 + e] = g;
    if (g != 0.0f) atomicAdd(out + 64 * 64 + e, g);
}

extern "C" void kernel_launch(void* const* d_in, const int* in_sizes, int n_in,
                              void* d_out, int out_size, void* d_ws, size_t ws_size,
                              hipStream_t stream) {
    const int*   task_id = (const int*)d_in[0];
    const float* x       = (const float*)d_in[1];
    const float* noise   = (const float*)d_in[2];
    const float* mlp_w1  = (const float*)d_in[3];
    const float* mlp_b1  = (const float*)d_in[4];
    const float* mlp_w2  = (const float*)d_in[5];
    const float* mlp_b2  = (const float*)d_in[6];
    const float* conv1_w = (const float*)d_in[7];
    const float* conv1_b = (const float*)d_in[8];
    const float* conv2_w = (const float*)d_in[9];
    const float* conv2_b = (const float*)d_in[10];
    const float* deg_w   = (const float*)d_in[11];
    const float* deg_b   = (const float*)d_in[12];
    const float* keys    = (const float*)d_in[13];
    const float* gate_w  = (const float*)d_in[14];
    const float* gate_b  = (const float*)d_in[15];
    const float* noise_w = (const float*)d_in[16];
    const float* noise_b = (const float*)d_in[17];

    float* out  = (float*)d_out;
    float* feat = (float*)d_ws;

    build_frags_kernel<<<1, 256, 0, stream>>>(conv1_w, conv1_b, conv2_w,
                                              conv2_b, d_ws, out);
    dim3 gridA(16, 8, 64);
    conv_feat_kernel<<<gridA, 256, 0, stream>>>(x, d_ws, feat);
    router_gate_kernel<<<64, 64, 0, stream>>>(
        task_id, noise, mlp_w1, mlp_b1, mlp_w2, mlp_b2, deg_w, deg_b, keys,
        gate_w, gate_b, noise_w, noise_b, feat, out);
}

// Round 10
// 184.484 us; speedup vs baseline: 2.1125x; 2.1125x over previous
//
#include <hip/hip_runtime.h>
#include <math.h>

typedef __attribute__((ext_vector_type(8)))  short  short8;    // 8 bf16
typedef __attribute__((ext_vector_type(4)))  short  svec4;     // 4 bf16 (b64)
typedef __attribute__((ext_vector_type(4)))  float  floatx4;
typedef __attribute__((ext_vector_type(16))) float  floatx16;
typedef __attribute__((ext_vector_type(2)))  unsigned uintx2;

__device__ __forceinline__ short bf16rne(float f) {
    unsigned u = __float_as_uint(f);
    unsigned r = (u + 0x7FFFu + ((u >> 16) & 1u)) >> 16;
    return (short)r;
}
__device__ __forceinline__ unsigned pk2(float a, float b) {
#if __has_builtin(__builtin_amdgcn_cvt_pk_bf16_f32)
    auto t = __builtin_amdgcn_cvt_pk_bf16_f32(a, b);
    unsigned u; __builtin_memcpy(&u, &t, 4); return u;
#else
    return (unsigned)(unsigned short)bf16rne(a) |
           ((unsigned)(unsigned short)bf16rne(b) << 16);
#endif
}

// ws: [0,8192) feat_sum; frags at 8192: 11 x 64 x 16B (W1a, W1b, B2[0..8]);
// conv1 C-init bias at +11264 (64 x float4); conv2 bias at +12288 (64 x f32)
#define WS_FRAG_OFF  8192
#define WS_BIAS1_OFF (WS_FRAG_OFF + 11 * 64 * 16)
#define WS_BIAS2_OFF (WS_BIAS1_OFF + 64 * 16)

#define PLANE_B 9792             // bytes per h1 ic-half plane (34*18 px * 16 B)

// ---------------------------------------------------------------------------
// Setup: build MFMA weight fragments + bias tables, zero feat & out-load.
// conv1 K-map: k = p*4 + c for positions p=0..7 (MFMA #1); position 8 in
// MFMA #2 at k=c (rest zero). c=3 is a zero pad channel.
// ---------------------------------------------------------------------------
__global__ __launch_bounds__(256) void build_frags_kernel(
    const float* __restrict__ w1,   // (16,3,9) = [oc][c][p]
    const float* __restrict__ b1,   // (16,)
    const float* __restrict__ w2,   // (32,16,9)
    const float* __restrict__ b2,   // (32,)
    void* __restrict__ ws,
    float* __restrict__ out)        // gates(4096) + load(64)
{
    const int t = threadIdx.x;
    float* feat = (float*)ws;
    for (int i = t; i < 2048; i += 256) feat[i] = 0.0f;
    if (t >= 64 && t < 128) out[4096 + (t - 64)] = 0.0f;

    if (t < 64) {
        const int lane = t;
        const int q = lane >> 4, ml = lane & 15;
        const int n32 = lane & 31, half = lane >> 5;
        short8* F = (short8*)((char*)ws + WS_FRAG_OFF);

        // W1a (A-operand, 16x16x32): A[m=ml=oc][k=q*8+j], p=q*2+(j>>2), c=j&3
        short8 W1a;
#pragma unroll
        for (int j = 0; j < 8; ++j) {
            int p = q * 2 + (j >> 2), c = j & 3;
            W1a[j] = (c < 3) ? bf16rne(w1[ml * 27 + c * 9 + p]) : (short)0;
        }
        F[0 * 64 + lane] = W1a;

        // W1b: position 8 only, k=c (q==0, j<3); zero elsewhere
        short8 W1b;
#pragma unroll
        for (int j = 0; j < 8; ++j) {
            W1b[j] = (q == 0 && j < 3) ? bf16rne(w1[ml * 27 + j * 9 + 8])
                                       : (short)0;
        }
        F[1 * 64 + lane] = W1b;

        // conv2 B-frags (32x32x16): B[k=half*8+j=ic][n=n32=oc] = w2[(oc*16+ic)*9+s]
#pragma unroll
        for (int s = 0; s < 9; ++s) {
            short8 Bs;
#pragma unroll
            for (int j = 0; j < 8; ++j) {
                int ic = half * 8 + j;
                Bs[j] = bf16rne(w2[(n32 * 16 + ic) * 9 + s]);
            }
            F[(2 + s) * 64 + lane] = Bs;
        }
        floatx4 bv;
#pragma unroll
        for (int r = 0; r < 4; ++r) bv[r] = b1[q * 4 + r];
        ((floatx4*)((char*)ws + WS_BIAS1_OFF))[lane] = bv;
        ((float*)((char*)ws + WS_BIAS2_OFF))[lane] = b2[n32];
    }
}

// one conv1 micro-tile: 3 b64 gathers, 2 MFMA, relu, pack, b64 store to the
// lane's ic-half plane position (wptr already includes plane + (q&1)*8).
__device__ __forceinline__ void conv1_tile(
    char* __restrict__ wptr, const char* __restrict__ inb,
    const int* lcB, int gbyte, int wbyte, bool valid, bool wmask,
    short8 W1a, short8 W1b, floatx4 biasv)
{
    svec4 r0 = *(const svec4*)(inb + gbyte + lcB[0]);
    svec4 r1 = *(const svec4*)(inb + gbyte + lcB[1]);
    svec4 r2 = *(const svec4*)(inb + gbyte + lcB[2]);
    short8 Bx, By;
    Bx[0]=r0[0]; Bx[1]=r0[1]; Bx[2]=r0[2]; Bx[3]=r0[3];
    Bx[4]=r1[0]; Bx[5]=r1[1]; Bx[6]=r1[2]; Bx[7]=r1[3];
    By[0]=r2[0]; By[1]=r2[1]; By[2]=r2[2]; By[3]=r2[3];
    By[4]=r2[0]; By[5]=r2[1]; By[6]=r2[2]; By[7]=r2[3];   // W1b=0 for k>=4
    floatx4 acc = biasv;
    acc = __builtin_amdgcn_mfma_f32_16x16x32_bf16(W1a, Bx, acc, 0, 0, 0);
    acc = __builtin_amdgcn_mfma_f32_16x16x32_bf16(W1b, By, acc, 0, 0, 0);
    float v0 = fmaxf(acc[0], 0.f), v1 = fmaxf(acc[1], 0.f);
    float v2 = fmaxf(acc[2], 0.f), v3 = fmaxf(acc[3], 0.f);
    if (!valid) { v0 = 0.f; v1 = 0.f; v2 = 0.f; v3 = 0.f; }
    if (wmask) {
        uintx2 w; w.x = pk2(v0, v1); w.y = pk2(v2, v3);
        *(uintx2*)(wptr + wbyte) = w;
    }
}

// ---------------------------------------------------------------------------
// Kernel A: 32(rows)x16(cols) output tile per block. __launch_bounds__(256,4):
// 128-VGPR budget fits ~110 live regs WITHOUT spill (r9's (256,6) forced an
// ~85-VGPR cap -> 550 MB scratch traffic, 4x regression). 4 blocks/CU.
// conv1+relu (2x 16x16x32 MFMA) -> conv2+relu (32x32x16 MFMA, 9-shift,
// sliding A-window) -> spatial sum -> atomicAdd feat_sum[B][32].
// ---------------------------------------------------------------------------
__global__ __launch_bounds__(256, 4) void conv_feat_kernel(
    const float* __restrict__ x,      // (64,3,256,256)
    const void*  __restrict__ ws_ro,
    float* __restrict__ feat_sum)     // (64,32)
{
    __shared__ short s_in4[36 * 20 * 4];   // bf16 [r][col][c pad4] (5760 B)
    __shared__ short s_h1[2 * 4896];       // two ic-half planes 34x18 px (19584 B)
    __shared__ float s_part[4][32];

    const int t    = threadIdx.x;
    const int lane = t & 63, wv = t >> 6;
    const int q    = lane >> 4, ml = lane & 15;
    const int n32  = lane & 31, half = lane >> 5;
    const int tx = blockIdx.x, ty = blockIdx.y, b = blockIdx.z;
    const bool border = (tx == 0) | (tx == 15) | (ty == 0) | (ty == 7);

    // ---- weight fragments / biases ----
    const short8* F = (const short8*)((const char*)ws_ro + WS_FRAG_OFF);
    short8 W1a = F[0 * 64 + lane];
    short8 W1b = F[1 * 64 + lane];
    short8 B2[9];
#pragma unroll
    for (int s = 0; s < 9; ++s) B2[s] = F[(2 + s) * 64 + lane];
    floatx4 biasv = ((const floatx4*)((const char*)ws_ro + WS_BIAS1_OFF))[lane];
    float   b2v   = ((const float*)((const char*)ws_ro + WS_BIAS2_OFF))[lane];

    // conv1 gather byte offsets (row stride 20 px * 8 B): positions q*2,q*2+1,8
    int lcB[3];
    {
        int p0 = q * 2, p1 = q * 2 + 1;
        lcB[0] = ((p0 / 3) * 20 + p0 % 3) * 8;
        lcB[1] = ((p1 / 3) * 20 + p1 % 3) * 8;
        lcB[2] = (2 * 20 + 2) * 8;
    }

    // ---- stage input tile as bf16 [r][col][4] (halo 2): 36 rows x 20 cols ----
    const int gy0 = ty * 32 - 2, gx0 = tx * 16 - 2;
    const float* xb = x + (size_t)b * 3 * 65536;
    if (!border) {
        for (int i = t; i < 720; i += 256) {
            int r = i / 20, c = i - r * 20;
            const float* p = xb + (gy0 + r) * 256 + gx0 + c;
            float v0 = p[0], v1 = p[65536], v2 = p[131072];
            uintx2 w; w.x = pk2(v0, v1); w.y = pk2(v2, 0.f);
            *(uintx2*)&s_in4[i * 4] = w;
        }
    } else {
        for (int i = t; i < 720; i += 256) {
            int r = i / 20, c = i - r * 20;
            int gy = gy0 + r, gx = gx0 + c;
            float v0 = 0.f, v1 = 0.f, v2 = 0.f;
            if ((unsigned)gy < 256u && (unsigned)gx < 256u) {
                const float* p = xb + gy * 256 + gx;
                v0 = p[0]; v1 = p[65536]; v2 = p[131072];
            }
            uintx2 w; w.x = pk2(v0, v1); w.y = pk2(v2, 0.f);
            *(uintx2*)&s_in4[i * 4] = w;
        }
    }
    __syncthreads();

    // ---- conv1 over 34x18 h1: 34 row-units + 4 col-units + corner ----
    char* wptr = (char*)s_h1 + (q >> 1) * PLANE_B + (q & 1) * 8;
    const char* inb = (const char*)s_in4;
    const int mlb = ml * 8;
    if (!border) {
#pragma unroll
        for (int i = 0; i < 8; ++i) {
            int u = wv * 8 + i;          // rows 0..31, cols 0..15
            conv1_tile(wptr, inb, lcB, u * 160 + mlb,
                       (u * 18 + ml) * 16, true, true, W1a, W1b, biasv);
        }
        if (wv < 2) {                    // rows 32,33
            int u = 32 + wv;
            conv1_tile(wptr, inb, lcB, u * 160 + mlb,
                       (u * 18 + ml) * 16, true, true, W1a, W1b, biasv);
        }
        {   // col unit: rows wv*8+(ml>>1), col 16+(ml&1)
            int rr = wv * 8 + (ml >> 1), cc = 16 + (ml & 1);
            conv1_tile(wptr, inb, lcB, rr * 160 + cc * 8,
                       (rr * 18 + cc) * 16, true, true, W1a, W1b, biasv);
        }
        if (wv == 2) {   // corner 4 px: rows 32-33 x cols 16-17
            int ml2 = ml & 3;
            int iy = 32 + (ml2 >> 1), ix = 16 + (ml2 & 1);
            conv1_tile(wptr, inb, lcB, iy * 160 + ix * 8,
                       (iy * 18 + ix) * 16, true, ml < 4, W1a, W1b, biasv);
        }
    } else {
        const bool gxOK = (unsigned)(tx * 16 - 1 + ml) < 256u;
#pragma unroll
        for (int i = 0; i < 8; ++i) {
            int u = wv * 8 + i;
            bool ok = ((unsigned)(ty * 32 - 1 + u) < 256u) & gxOK;
            conv1_tile(wptr, inb, lcB, u * 160 + mlb,
                       (u * 18 + ml) * 16, ok, true, W1a, W1b, biasv);
        }
        if (wv < 2) {
            int u = 32 + wv;
            bool ok = ((unsigned)(ty * 32 - 1 + u) < 256u) & gxOK;
            conv1_tile(wptr, inb, lcB, u * 160 + mlb,
                       (u * 18 + ml) * 16, ok, true, W1a, W1b, biasv);
        }
        {
            int rr = wv * 8 + (ml >> 1), cc = 16 + (ml & 1);
            bool ok = ((unsigned)(ty * 32 - 1 + rr) < 256u) &
                      ((unsigned)(tx * 16 - 1 + cc) < 256u);
            conv1_tile(wptr, inb, lcB, rr * 160 + cc * 8,
                       (rr * 18 + cc) * 16, ok, true, W1a, W1b, biasv);
        }
        if (wv == 2) {
            int ml2 = ml & 3;
            int iy = 32 + (ml2 >> 1), ix = 16 + (ml2 & 1);
            bool ok = ((unsigned)(ty * 32 - 1 + iy) < 256u) &
                      ((unsigned)(tx * 16 - 1 + ix) < 256u);
            conv1_tile(wptr, inb, lcB, iy * 160 + ix * 8,
                       (iy * 18 + ix) * 16, ok, ml < 4, W1a, W1b, biasv);
        }
    }
    __syncthreads();

    // ---- conv2: wave = 4 vertically-chained 32-px tiles (2 rows x 16 cols),
    //      rows wv*8..wv*8+7, sliding 3x3 A-frag window ----
    float part = 0.0f;
    {
        const int prow0 = n32 >> 4, pcol = n32 & 15;
        const char* pl = (const char*)s_h1 + half * PLANE_B;
        int pb = ((wv * 8 + prow0) * 18 + pcol) * 16;
        short8 Af[3][3];
#pragma unroll
        for (int ky = 0; ky < 3; ++ky)
#pragma unroll
            for (int kx = 0; kx < 3; ++kx)
                Af[ky][kx] = *(const short8*)(pl + pb + (ky * 18 + kx) * 16);
#pragma unroll
        for (int it = 0; it < 4; ++it) {
            const int rb = (2 * it) % 3;
            floatx16 acc;
#pragma unroll
            for (int r = 0; r < 16; ++r) acc[r] = b2v;
#pragma unroll
            for (int s = 0; s < 9; ++s) {
                const int ky = s / 3, kx = s % 3;
                acc = __builtin_amdgcn_mfma_f32_32x32x16_bf16(
                        Af[(rb + ky) % 3][kx], B2[s], acc, 0, 0, 0);
            }
#pragma unroll
            for (int r = 0; r < 16; ++r) part += fmaxf(acc[r], 0.0f);
            if (it < 3) {
                pb += 576;   // advance 2 h1 rows (2*18*16 B)
#pragma unroll
                for (int kx = 0; kx < 3; ++kx) {
                    Af[rb][kx] =
                        *(const short8*)(pl + pb + (18 + kx) * 16);
                    Af[(rb + 1) % 3][kx] =
                        *(const short8*)(pl + pb + (36 + kx) * 16);
                }
            }
        }
    }
    part += __shfl_xor(part, 32);
    if (lane < 32) s_part[wv][n32] = part;
    __syncthreads();
    if (t < 32) {
        float ssum = s_part[0][t] + s_part[1][t] + s_part[2][t] + s_part[3][t];
        atomicAdd(feat_sum + b * 32 + t, ssum);
    }
}

// ---------------------------------------------------------------------------
// Kernel B: gating. One block per batch row, 64 threads (= experts, 1 wave).
// ---------------------------------------------------------------------------
__global__ __launch_bounds__(64) void router_gate_kernel(
    const int* __restrict__ task_id,
    const float* __restrict__ noise,
    const float* __restrict__ mlp_w1,
    const float* __restrict__ mlp_b1,
    const float* __restrict__ mlp_w2,
    const float* __restrict__ mlp_b2,
    const float* __restrict__ deg_w,
    const float* __restrict__ deg_b,
    const float* __restrict__ keys,
    const float* __restrict__ gate_w,
    const float* __restrict__ gate_b,
    const float* __restrict__ noise_w,
    const float* __restrict__ noise_b,
    const float* __restrict__ feat_sum,
    float* __restrict__ out)
{
    const int b = blockIdx.x;
    const int e = threadIdx.x;

    __shared__ float s_te[32];
    __shared__ float s_comb[32];
    __shared__ float s_ew[64];

    if (e < 32) {
        float tf = (float)task_id[b];
        s_te[e] = fmaxf(tf * mlp_w1[e] + mlp_b1[e], 0.0f);
    }
    __syncthreads();
    if (e < 32) {
        float acc = mlp_b2[e];
        for (int k = 0; k < 32; ++k) acc += s_te[k] * mlp_w2[k * 32 + e];
        float dacc = deg_b[e];
        for (int c = 0; c < 32; ++c)
            dacc += (feat_sum[b * 32 + c] * (1.0f / 65536.0f)) * deg_w[c * 32 + e];
        s_comb[e] = acc + 0.2f * dacc;  // ALPHA = 0.8
    }
    __syncthreads();

    float s = 0.0f;
    for (int d = 0; d < 32; ++d) s += s_comb[d] * keys[e * 32 + d];
    s *= 0.17677669529663687f;  // 1/sqrt(32)

    float m = s;
    for (int off = 32; off; off >>= 1) m = fmaxf(m, __shfl_xor(m, off));
    float p = expf(s - m);
    float sum = p;
    for (int off = 32; off; off >>= 1) sum += __shfl_xor(sum, off);
    float w = p / sum;
    s_ew[e] = w;
    __syncthreads();

    float cl = gate_b[e], nz = noise_b[e];
    for (int k = 0; k < 64; ++k) {
        float ewk = s_ew[k];
        cl += ewk * gate_w[k * 64 + e];
        nz += ewk * noise_w[k * 64 + e];
    }
    float sp = (nz > 20.0f) ? nz : log1pf(expf(nz));
    float logit = cl + noise[b * 64 + e] * (sp + 0.01f);

    float v0 = logit; int i0 = e;
    for (int off = 32; off; off >>= 1) {
        float ov = __shfl_xor(v0, off);
        int   oi = __shfl_xor(i0, off);
        if (ov > v0 || (ov == v0 && oi < i0)) { v0 = ov; i0 = oi; }
    }
    float v1 = (e == i0) ? -INFINITY : logit; int i1 = e;
    for (int off = 32; off; off >>= 1) {
        float ov = __shfl_xor(v1, off);
        int   oi = __shfl_xor(i1, off);
        if (ov > v1 || (ov == v1 && oi < i1)) { v1 = ov; i1 = oi; }
    }

    float e1 = expf(v1 - v0);
    float g0 = 1.0f / (1.0f + e1);
    float g1 = e1 / (1.0f + e1);

    float g = (e == i0) ? g0 : (e == i1) ? g1 : 0.0f;
    out[b * 64 + e] = g;
    if (g != 0.0f) atomicAdd(out + 64 * 64 + e, g);
}

extern "C" void kernel_launch(void* const* d_in, const int* in_sizes, int n_in,
                              void* d_out, int out_size, void* d_ws, size_t ws_size,
                              hipStream_t stream) {
    const int*   task_id = (const int*)d_in[0];
    const float* x       = (const float*)d_in[1];
    const float* noise   = (const float*)d_in[2];
    const float* mlp_w1  = (const float*)d_in[3];
    const float* mlp_b1  = (const float*)d_in[4];
    const float* mlp_w2  = (const float*)d_in[5];
    const float* mlp_b2  = (const float*)d_in[6];
    const float* conv1_w = (const float*)d_in[7];
    const float* conv1_b = (const float*)d_in[8];
    const float* conv2_w = (const float*)d_in[9];
    const float* conv2_b = (const float*)d_in[10];
    const float* deg_w   = (const float*)d_in[11];
    const float* deg_b   = (const float*)d_in[12];
    const float* keys    = (const float*)d_in[13];
    const float* gate_w  = (const float*)d_in[14];
    const float* gate_b  = (const float*)d_in[15];
    const float* noise_w = (const float*)d_in[16];
    const float* noise_b = (const float*)d_in[17];

    float* out  = (float*)d_out;
    float* feat = (float*)d_ws;

    build_frags_kernel<<<1, 256, 0, stream>>>(conv1_w, conv1_b, conv2_w,
                                              conv2_b, d_ws, out);
    dim3 gridA(16, 8, 64);
    conv_feat_kernel<<<gridA, 256, 0, stream>>>(x, d_ws, feat);
    router_gate_kernel<<<64, 64, 0, stream>>>(
        task_id, noise, mlp_w1, mlp_b1, mlp_w2, mlp_b2, deg_w, deg_b, keys,
        gate_w, gate_b, noise_w, noise_b, feat, out);
}

// Round 11
// 181.416 us; speedup vs baseline: 2.1482x; 1.0169x over previous
//
#include <hip/hip_runtime.h>
#include <math.h>

typedef __attribute__((ext_vector_type(8)))  short  short8;    // 8 bf16
typedef __attribute__((ext_vector_type(4)))  short  svec4;     // 4 bf16 (b64)
typedef __attribute__((ext_vector_type(4)))  float  floatx4;
typedef __attribute__((ext_vector_type(16))) float  floatx16;
typedef __attribute__((ext_vector_type(2)))  unsigned uintx2;

__device__ __forceinline__ short bf16rne(float f) {
    unsigned u = __float_as_uint(f);
    unsigned r = (u + 0x7FFFu + ((u >> 16) & 1u)) >> 16;
    return (short)r;
}
__device__ __forceinline__ unsigned pk2(float a, float b) {
#if __has_builtin(__builtin_amdgcn_cvt_pk_bf16_f32)
    auto t = __builtin_amdgcn_cvt_pk_bf16_f32(a, b);
    unsigned u; __builtin_memcpy(&u, &t, 4); return u;
#else
    return (unsigned)(unsigned short)bf16rne(a) |
           ((unsigned)(unsigned short)bf16rne(b) << 16);
#endif
}

// ws: [0,8192) feat_sum; frags at 8192: 11 x 64 x 16B (W1a, W1b, B2[0..8]);
// conv1 C-init bias at +11264 (64 x float4); conv2 bias at +12288 (64 x f32)
#define WS_FRAG_OFF  8192
#define WS_BIAS1_OFF (WS_FRAG_OFF + 11 * 64 * 16)
#define WS_BIAS2_OFF (WS_BIAS1_OFF + 64 * 16)

#define PLANE_B 9792             // bytes per h1 ic-half plane (34*18 px * 16 B)

// ---------------------------------------------------------------------------
// Setup: build MFMA weight fragments + bias tables, zero feat & out-load.
// conv1 K-map: k = p*4 + c for positions p=0..7 (MFMA #1); position 8 in
// MFMA #2 at k=c (rest zero). c=3 is a zero pad channel.
// ---------------------------------------------------------------------------
__global__ __launch_bounds__(256) void build_frags_kernel(
    const float* __restrict__ w1,   // (16,3,9) = [oc][c][p]
    const float* __restrict__ b1,   // (16,)
    const float* __restrict__ w2,   // (32,16,9)
    const float* __restrict__ b2,   // (32,)
    void* __restrict__ ws,
    float* __restrict__ out)        // gates(4096) + load(64)
{
    const int t = threadIdx.x;
    float* feat = (float*)ws;
    for (int i = t; i < 2048; i += 256) feat[i] = 0.0f;
    if (t >= 64 && t < 128) out[4096 + (t - 64)] = 0.0f;

    if (t < 64) {
        const int lane = t;
        const int q = lane >> 4, ml = lane & 15;
        const int n32 = lane & 31, half = lane >> 5;
        short8* F = (short8*)((char*)ws + WS_FRAG_OFF);

        // W1a (A-operand, 16x16x32): A[m=ml=oc][k=q*8+j], p=q*2+(j>>2), c=j&3
        short8 W1a;
#pragma unroll
        for (int j = 0; j < 8; ++j) {
            int p = q * 2 + (j >> 2), c = j & 3;
            W1a[j] = (c < 3) ? bf16rne(w1[ml * 27 + c * 9 + p]) : (short)0;
        }
        F[0 * 64 + lane] = W1a;

        // W1b: position 8 only, k=c (q==0, j<3); zero elsewhere
        short8 W1b;
#pragma unroll
        for (int j = 0; j < 8; ++j) {
            W1b[j] = (q == 0 && j < 3) ? bf16rne(w1[ml * 27 + j * 9 + 8])
                                       : (short)0;
        }
        F[1 * 64 + lane] = W1b;

        // conv2 B-frags (32x32x16): B[k=half*8+j=ic][n=n32=oc] = w2[(oc*16+ic)*9+s]
#pragma unroll
        for (int s = 0; s < 9; ++s) {
            short8 Bs;
#pragma unroll
            for (int j = 0; j < 8; ++j) {
                int ic = half * 8 + j;
                Bs[j] = bf16rne(w2[(n32 * 16 + ic) * 9 + s]);
            }
            F[(2 + s) * 64 + lane] = Bs;
        }
        floatx4 bv;
#pragma unroll
        for (int r = 0; r < 4; ++r) bv[r] = b1[q * 4 + r];
        ((floatx4*)((char*)ws + WS_BIAS1_OFF))[lane] = bv;
        ((float*)((char*)ws + WS_BIAS2_OFF))[lane] = b2[n32];
    }
}

// one conv1 micro-tile: 3 b64 gathers, 2 MFMA, relu, pack, b64 store to the
// lane's ic-half plane position (wptr already includes plane + (q&1)*8).
__device__ __forceinline__ void conv1_tile(
    char* __restrict__ wptr, const char* __restrict__ inb,
    const int* lcB, int gbyte, int wbyte, bool valid, bool wmask,
    short8 W1a, short8 W1b, floatx4 biasv)
{
    svec4 r0 = *(const svec4*)(inb + gbyte + lcB[0]);
    svec4 r1 = *(const svec4*)(inb + gbyte + lcB[1]);
    svec4 r2 = *(const svec4*)(inb + gbyte + lcB[2]);
    short8 Bx, By;
    Bx[0]=r0[0]; Bx[1]=r0[1]; Bx[2]=r0[2]; Bx[3]=r0[3];
    Bx[4]=r1[0]; Bx[5]=r1[1]; Bx[6]=r1[2]; Bx[7]=r1[3];
    By[0]=r2[0]; By[1]=r2[1]; By[2]=r2[2]; By[3]=r2[3];
    By[4]=r2[0]; By[5]=r2[1]; By[6]=r2[2]; By[7]=r2[3];   // W1b=0 for k>=4
    floatx4 acc = biasv;
    acc = __builtin_amdgcn_mfma_f32_16x16x32_bf16(W1a, Bx, acc, 0, 0, 0);
    acc = __builtin_amdgcn_mfma_f32_16x16x32_bf16(W1b, By, acc, 0, 0, 0);
    float v0 = fmaxf(acc[0], 0.f), v1 = fmaxf(acc[1], 0.f);
    float v2 = fmaxf(acc[2], 0.f), v3 = fmaxf(acc[3], 0.f);
    if (!valid) { v0 = 0.f; v1 = 0.f; v2 = 0.f; v3 = 0.f; }
    if (wmask) {
        uintx2 w; w.x = pk2(v0, v1); w.y = pk2(v2, v3);
        *(uintx2*)(wptr + wbyte) = w;
    }
}

// ---------------------------------------------------------------------------
// Kernel A: 32(rows)x16(cols) output tile per block, __launch_bounds__(256,4)
// (unified VGPR+AGPR budget = 128; r10 spilled because B2[9]+Af[3][3]+acc16
// = ~135 live regs -> this version loads B2 AFTER conv1 and drops the
// sliding A-window so peak demand ~100, zero spill). 4 blocks/CU.
// conv1+relu (2x 16x16x32 MFMA) -> conv2+relu (32x32x16 MFMA, 9-shift)
// -> spatial sum -> atomicAdd feat_sum[B][32].
// ---------------------------------------------------------------------------
__global__ __launch_bounds__(256, 4) void conv_feat_kernel(
    const float* __restrict__ x,      // (64,3,256,256)
    const void*  __restrict__ ws_ro,
    float* __restrict__ feat_sum)     // (64,32)
{
    __shared__ short s_in4[36 * 20 * 4];   // bf16 [r][col][c pad4] (5760 B)
    __shared__ short s_h1[2 * 4896];       // two ic-half planes 34x18 px (19584 B)
    __shared__ float s_part[4][32];

    const int t    = threadIdx.x;
    const int lane = t & 63, wv = t >> 6;
    const int q    = lane >> 4, ml = lane & 15;
    const int n32  = lane & 31, half = lane >> 5;
    const int tx = blockIdx.x, ty = blockIdx.y, b = blockIdx.z;
    const bool border = (tx == 0) | (tx == 15) | (ty == 0) | (ty == 7);

    // ---- conv1 weight fragments / bias only (B2 loaded after conv1) ----
    const short8* F = (const short8*)((const char*)ws_ro + WS_FRAG_OFF);
    short8 W1a = F[0 * 64 + lane];
    short8 W1b = F[1 * 64 + lane];
    floatx4 biasv = ((const floatx4*)((const char*)ws_ro + WS_BIAS1_OFF))[lane];

    // conv1 gather byte offsets (row stride 20 px * 8 B): positions q*2,q*2+1,8
    int lcB[3];
    {
        int p0 = q * 2, p1 = q * 2 + 1;
        lcB[0] = ((p0 / 3) * 20 + p0 % 3) * 8;
        lcB[1] = ((p1 / 3) * 20 + p1 % 3) * 8;
        lcB[2] = (2 * 20 + 2) * 8;
    }

    // ---- stage input tile as bf16 [r][col][4] (halo 2): 36 rows x 20 cols ----
    const int gy0 = ty * 32 - 2, gx0 = tx * 16 - 2;
    const float* xb = x + (size_t)b * 3 * 65536;
    if (!border) {
        for (int i = t; i < 720; i += 256) {
            int r = i / 20, c = i - r * 20;
            const float* p = xb + (gy0 + r) * 256 + gx0 + c;
            float v0 = p[0], v1 = p[65536], v2 = p[131072];
            uintx2 w; w.x = pk2(v0, v1); w.y = pk2(v2, 0.f);
            *(uintx2*)&s_in4[i * 4] = w;
        }
    } else {
        for (int i = t; i < 720; i += 256) {
            int r = i / 20, c = i - r * 20;
            int gy = gy0 + r, gx = gx0 + c;
            float v0 = 0.f, v1 = 0.f, v2 = 0.f;
            if ((unsigned)gy < 256u && (unsigned)gx < 256u) {
                const float* p = xb + gy * 256 + gx;
                v0 = p[0]; v1 = p[65536]; v2 = p[131072];
            }
            uintx2 w; w.x = pk2(v0, v1); w.y = pk2(v2, 0.f);
            *(uintx2*)&s_in4[i * 4] = w;
        }
    }
    __syncthreads();

    // ---- conv1 over 34x18 h1: 34 row-units + 4 col-units + corner ----
    char* wptr = (char*)s_h1 + (q >> 1) * PLANE_B + (q & 1) * 8;
    const char* inb = (const char*)s_in4;
    const int mlb = ml * 8;
    if (!border) {
#pragma unroll
        for (int i = 0; i < 8; ++i) {
            int u = wv * 8 + i;          // rows 0..31, cols 0..15
            conv1_tile(wptr, inb, lcB, u * 160 + mlb,
                       (u * 18 + ml) * 16, true, true, W1a, W1b, biasv);
        }
        if (wv < 2) {                    // rows 32,33
            int u = 32 + wv;
            conv1_tile(wptr, inb, lcB, u * 160 + mlb,
                       (u * 18 + ml) * 16, true, true, W1a, W1b, biasv);
        }
        {   // col unit: rows wv*8+(ml>>1), col 16+(ml&1)
            int rr = wv * 8 + (ml >> 1), cc = 16 + (ml & 1);
            conv1_tile(wptr, inb, lcB, rr * 160 + cc * 8,
                       (rr * 18 + cc) * 16, true, true, W1a, W1b, biasv);
        }
        if (wv == 2) {   // corner 4 px: rows 32-33 x cols 16-17
            int ml2 = ml & 3;
            int iy = 32 + (ml2 >> 1), ix = 16 + (ml2 & 1);
            conv1_tile(wptr, inb, lcB, iy * 160 + ix * 8,
                       (iy * 18 + ix) * 16, true, ml < 4, W1a, W1b, biasv);
        }
    } else {
        const bool gxOK = (unsigned)(tx * 16 - 1 + ml) < 256u;
#pragma unroll
        for (int i = 0; i < 8; ++i) {
            int u = wv * 8 + i;
            bool ok = ((unsigned)(ty * 32 - 1 + u) < 256u) & gxOK;
            conv1_tile(wptr, inb, lcB, u * 160 + mlb,
                       (u * 18 + ml) * 16, ok, true, W1a, W1b, biasv);
        }
        if (wv < 2) {
            int u = 32 + wv;
            bool ok = ((unsigned)(ty * 32 - 1 + u) < 256u) & gxOK;
            conv1_tile(wptr, inb, lcB, u * 160 + mlb,
                       (u * 18 + ml) * 16, ok, true, W1a, W1b, biasv);
        }
        {
            int rr = wv * 8 + (ml >> 1), cc = 16 + (ml & 1);
            bool ok = ((unsigned)(ty * 32 - 1 + rr) < 256u) &
                      ((unsigned)(tx * 16 - 1 + cc) < 256u);
            conv1_tile(wptr, inb, lcB, rr * 160 + cc * 8,
                       (rr * 18 + cc) * 16, ok, true, W1a, W1b, biasv);
        }
        if (wv == 2) {
            int ml2 = ml & 3;
            int iy = 32 + (ml2 >> 1), ix = 16 + (ml2 & 1);
            bool ok = ((unsigned)(ty * 32 - 1 + iy) < 256u) &
                      ((unsigned)(tx * 16 - 1 + ix) < 256u);
            conv1_tile(wptr, inb, lcB, iy * 160 + ix * 8,
                       (iy * 18 + ix) * 16, ok, ml < 4, W1a, W1b, biasv);
        }
    }
    __syncthreads();

    // ---- conv2: B2 loaded here (post-conv1, lowers conv1-phase pressure);
    //      wave = 4x 32-px tiles (2 rows x 16 cols), rows wv*8..wv*8+7;
    //      A-frags loaded per ky-row (no persistent window -> no spill) ----
    short8 B2[9];
#pragma unroll
    for (int s = 0; s < 9; ++s) B2[s] = F[(2 + s) * 64 + lane];
    float b2v = ((const float*)((const char*)ws_ro + WS_BIAS2_OFF))[lane];

    float part = 0.0f;
    {
        const int prow0 = n32 >> 4, pcol = n32 & 15;
        const char* pl = (const char*)s_h1 + half * PLANE_B;
#pragma unroll
        for (int it = 0; it < 4; ++it) {
            const int pb = ((wv * 8 + 2 * it + prow0) * 18 + pcol) * 16;
            floatx16 acc;
#pragma unroll
            for (int r = 0; r < 16; ++r) acc[r] = b2v;
#pragma unroll
            for (int ky = 0; ky < 3; ++ky) {
                const char* rp = pl + pb + ky * 288;   // 18 px * 16 B
                short8 A0 = *(const short8*)(rp);
                short8 A1 = *(const short8*)(rp + 16);
                short8 A2 = *(const short8*)(rp + 32);
                acc = __builtin_amdgcn_mfma_f32_32x32x16_bf16(A0, B2[ky * 3 + 0], acc, 0, 0, 0);
                acc = __builtin_amdgcn_mfma_f32_32x32x16_bf16(A1, B2[ky * 3 + 1], acc, 0, 0, 0);
                acc = __builtin_amdgcn_mfma_f32_32x32x16_bf16(A2, B2[ky * 3 + 2], acc, 0, 0, 0);
            }
#pragma unroll
            for (int r = 0; r < 16; ++r) part += fmaxf(acc[r], 0.0f);
        }
    }
    part += __shfl_xor(part, 32);
    if (lane < 32) s_part[wv][n32] = part;
    __syncthreads();
    if (t < 32) {
        float ssum = s_part[0][t] + s_part[1][t] + s_part[2][t] + s_part[3][t];
        atomicAdd(feat_sum + b * 32 + t, ssum);
    }
}

// ---------------------------------------------------------------------------
// Kernel B: gating. One block per batch row, 64 threads (= experts, 1 wave).
// ---------------------------------------------------------------------------
__global__ __launch_bounds__(64) void router_gate_kernel(
    const int* __restrict__ task_id,
    const float* __restrict__ noise,
    const float* __restrict__ mlp_w1,
    const float* __restrict__ mlp_b1,
    const float* __restrict__ mlp_w2,
    const float* __restrict__ mlp_b2,
    const float* __restrict__ deg_w,
    const float* __restrict__ deg_b,
    const float* __restrict__ keys,
    const float* __restrict__ gate_w,
    const float* __restrict__ gate_b,
    const float* __restrict__ noise_w,
    const float* __restrict__ noise_b,
    const float* __restrict__ feat_sum,
    float* __restrict__ out)
{
    const int b = blockIdx.x;
    const int e = threadIdx.x;

    __shared__ float s_te[32];
    __shared__ float s_comb[32];
    __shared__ float s_ew[64];

    if (e < 32) {
        float tf = (float)task_id[b];
        s_te[e] = fmaxf(tf * mlp_w1[e] + mlp_b1[e], 0.0f);
    }
    __syncthreads();
    if (e < 32) {
        float acc = mlp_b2[e];
        for (int k = 0; k < 32; ++k) acc += s_te[k] * mlp_w2[k * 32 + e];
        float dacc = deg_b[e];
        for (int c = 0; c < 32; ++c)
            dacc += (feat_sum[b * 32 + c] * (1.0f / 65536.0f)) * deg_w[c * 32 + e];
        s_comb[e] = acc + 0.2f * dacc;  // ALPHA = 0.8
    }
    __syncthreads();

    float s = 0.0f;
    for (int d = 0; d < 32; ++d) s += s_comb[d] * keys[e * 32 + d];
    s *= 0.17677669529663687f;  // 1/sqrt(32)

    float m = s;
    for (int off = 32; off; off >>= 1) m = fmaxf(m, __shfl_xor(m, off));
    float p = expf(s - m);
    float sum = p;
    for (int off = 32; off; off >>= 1) sum += __shfl_xor(sum, off);
    float w = p / sum;
    s_ew[e] = w;
    __syncthreads();

    float cl = gate_b[e], nz = noise_b[e];
    for (int k = 0; k < 64; ++k) {
        float ewk = s_ew[k];
        cl += ewk * gate_w[k * 64 + e];
        nz += ewk * noise_w[k * 64 + e];
    }
    float sp = (nz > 20.0f) ? nz : log1pf(expf(nz));
    float logit = cl + noise[b * 64 + e] * (sp + 0.01f);

    float v0 = logit; int i0 = e;
    for (int off = 32; off; off >>= 1) {
        float ov = __shfl_xor(v0, off);
        int   oi = __shfl_xor(i0, off);
        if (ov > v0 || (ov == v0 && oi < i0)) { v0 = ov; i0 = oi; }
    }
    float v1 = (e == i0) ? -INFINITY : logit; int i1 = e;
    for (int off = 32; off; off >>= 1) {
        float ov = __shfl_xor(v1, off);
        int   oi = __shfl_xor(i1, off);
        if (ov > v1 || (ov == v1 && oi < i1)) { v1 = ov; i1 = oi; }
    }

    float e1 = expf(v1 - v0);
    float g0 = 1.0f / (1.0f + e1);
    float g1 = e1 / (1.0f + e1);

    float g = (e == i0) ? g0 : (e == i1) ? g1 : 0.0f;
    out[b * 64 + e] = g;
    if (g != 0.0f) atomicAdd(out + 64 * 64 + e, g);
}

extern "C" void kernel_launch(void* const* d_in, const int* in_sizes, int n_in,
                              void* d_out, int out_size, void* d_ws, size_t ws_size,
                              hipStream_t stream) {
    const int*   task_id = (const int*)d_in[0];
    const float* x       = (const float*)d_in[1];
    const float* noise   = (const float*)d_in[2];
    const float* mlp_w1  = (const float*)d_in[3];
    const float* mlp_b1  = (const float*)d_in[4];
    const float* mlp_w2  = (const float*)d_in[5];
    const float* mlp_b2  = (const float*)d_in[6];
    const float* conv1_w = (const float*)d_in[7];
    const float* conv1_b = (const float*)d_in[8];
    const float* conv2_w = (const float*)d_in[9];
    const float* conv2_b = (const float*)d_in[10];
    const float* deg_w   = (const float*)d_in[11];
    const float* deg_b   = (const float*)d_in[12];
    const float* keys    = (const float*)d_in[13];
    const float* gate_w  = (const float*)d_in[14];
    const float* gate_b  = (const float*)d_in[15];
    const float* noise_w = (const float*)d_in[16];
    const float* noise_b = (const float*)d_in[17];

    float* out  = (float*)d_out;
    float* feat = (float*)d_ws;

    build_frags_kernel<<<1, 256, 0, stream>>>(conv1_w, conv1_b, conv2_w,
                                              conv2_b, d_ws, out);
    dim3 gridA(16, 8, 64);
    conv_feat_kernel<<<gridA, 256, 0, stream>>>(x, d_ws, feat);
    router_gate_kernel<<<64, 64, 0, stream>>>(
        task_id, noise, mlp_w1, mlp_b1, mlp_w2, mlp_b2, deg_w, deg_b, keys,
        gate_w, gate_b, noise_w, noise_b, feat, out);
}

// Round 12
// 178.048 us; speedup vs baseline: 2.1888x; 1.0189x over previous
//
#include <hip/hip_runtime.h>
#include <math.h>

typedef __attribute__((ext_vector_type(8)))  short  short8;    // 8 bf16
typedef __attribute__((ext_vector_type(4)))  short  svec4;     // 4 bf16 (b64)
typedef __attribute__((ext_vector_type(4)))  float  floatx4;
typedef __attribute__((ext_vector_type(16))) float  floatx16;
typedef __attribute__((ext_vector_type(2)))  unsigned uintx2;

__device__ __forceinline__ short bf16rne(float f) {
    unsigned u = __float_as_uint(f);
    unsigned r = (u + 0x7FFFu + ((u >> 16) & 1u)) >> 16;
    return (short)r;
}
__device__ __forceinline__ unsigned pk2(float a, float b) {
#if __has_builtin(__builtin_amdgcn_cvt_pk_bf16_f32)
    auto t = __builtin_amdgcn_cvt_pk_bf16_f32(a, b);
    unsigned u; __builtin_memcpy(&u, &t, 4); return u;
#else
    return (unsigned)(unsigned short)bf16rne(a) |
           ((unsigned)(unsigned short)bf16rne(b) << 16);
#endif
}

// ws: [0,8192) feat_sum; frags at 8192: 11 x 64 x 16B (W1a, W1b, B2[0..8]);
// conv1 C-init bias at +11264 (64 x float4); conv2 bias at +12288 (64 x f32)
#define WS_FRAG_OFF  8192
#define WS_BIAS1_OFF (WS_FRAG_OFF + 11 * 64 * 16)
#define WS_BIAS2_OFF (WS_BIAS1_OFF + 64 * 16)

#define PLANE_B 9792             // bytes per h1 ic-half plane (34*18 px * 16 B)

// ---------------------------------------------------------------------------
// Setup: build MFMA weight fragments + bias tables, zero feat & out-load.
// conv1 K-map: k = p*4 + c for positions p=0..7 (MFMA #1); position 8 in
// MFMA #2 at k=c (rest zero). c=3 is a zero pad channel.
// ---------------------------------------------------------------------------
__global__ __launch_bounds__(256) void build_frags_kernel(
    const float* __restrict__ w1,   // (16,3,9) = [oc][c][p]
    const float* __restrict__ b1,   // (16,)
    const float* __restrict__ w2,   // (32,16,9)
    const float* __restrict__ b2,   // (32,)
    void* __restrict__ ws,
    float* __restrict__ out)        // gates(4096) + load(64)
{
    const int t = threadIdx.x;
    float* feat = (float*)ws;
    for (int i = t; i < 2048; i += 256) feat[i] = 0.0f;
    if (t >= 64 && t < 128) out[4096 + (t - 64)] = 0.0f;

    if (t < 64) {
        const int lane = t;
        const int q = lane >> 4, ml = lane & 15;
        const int n32 = lane & 31, half = lane >> 5;
        short8* F = (short8*)((char*)ws + WS_FRAG_OFF);

        // W1a (A-operand, 16x16x32): A[m=ml=oc][k=q*8+j], p=q*2+(j>>2), c=j&3
        short8 W1a;
#pragma unroll
        for (int j = 0; j < 8; ++j) {
            int p = q * 2 + (j >> 2), c = j & 3;
            W1a[j] = (c < 3) ? bf16rne(w1[ml * 27 + c * 9 + p]) : (short)0;
        }
        F[0 * 64 + lane] = W1a;

        // W1b: position 8 only, k=c (q==0, j<3); zero elsewhere
        short8 W1b;
#pragma unroll
        for (int j = 0; j < 8; ++j) {
            W1b[j] = (q == 0 && j < 3) ? bf16rne(w1[ml * 27 + j * 9 + 8])
                                       : (short)0;
        }
        F[1 * 64 + lane] = W1b;

        // conv2 B-frags (32x32x16): B[k=half*8+j=ic][n=n32=oc] = w2[(oc*16+ic)*9+s]
#pragma unroll
        for (int s = 0; s < 9; ++s) {
            short8 Bs;
#pragma unroll
            for (int j = 0; j < 8; ++j) {
                int ic = half * 8 + j;
                Bs[j] = bf16rne(w2[(n32 * 16 + ic) * 9 + s]);
            }
            F[(2 + s) * 64 + lane] = Bs;
        }
        floatx4 bv;
#pragma unroll
        for (int r = 0; r < 4; ++r) bv[r] = b1[q * 4 + r];
        ((floatx4*)((char*)ws + WS_BIAS1_OFF))[lane] = bv;
        ((float*)((char*)ws + WS_BIAS2_OFF))[lane] = b2[n32];
    }
}

// one conv1 micro-tile: 3 b64 gathers, 2 MFMA, relu, pack, b64 store to the
// lane's ic-half plane position (wptr already includes plane + (q&1)*8).
__device__ __forceinline__ void conv1_tile(
    char* __restrict__ wptr, const char* __restrict__ inb,
    const int* lcB, int gbyte, int wbyte, bool valid, bool wmask,
    short8 W1a, short8 W1b, floatx4 biasv)
{
    svec4 r0 = *(const svec4*)(inb + gbyte + lcB[0]);
    svec4 r1 = *(const svec4*)(inb + gbyte + lcB[1]);
    svec4 r2 = *(const svec4*)(inb + gbyte + lcB[2]);
    short8 Bx, By;
    Bx[0]=r0[0]; Bx[1]=r0[1]; Bx[2]=r0[2]; Bx[3]=r0[3];
    Bx[4]=r1[0]; Bx[5]=r1[1]; Bx[6]=r1[2]; Bx[7]=r1[3];
    By[0]=r2[0]; By[1]=r2[1]; By[2]=r2[2]; By[3]=r2[3];
    By[4]=r2[0]; By[5]=r2[1]; By[6]=r2[2]; By[7]=r2[3];   // W1b=0 for k>=4
    floatx4 acc = biasv;
    acc = __builtin_amdgcn_mfma_f32_16x16x32_bf16(W1a, Bx, acc, 0, 0, 0);
    acc = __builtin_amdgcn_mfma_f32_16x16x32_bf16(W1b, By, acc, 0, 0, 0);
    float v0 = fmaxf(acc[0], 0.f), v1 = fmaxf(acc[1], 0.f);
    float v2 = fmaxf(acc[2], 0.f), v3 = fmaxf(acc[3], 0.f);
    if (!valid) { v0 = 0.f; v1 = 0.f; v2 = 0.f; v3 = 0.f; }
    if (wmask) {
        uintx2 w; w.x = pk2(v0, v1); w.y = pk2(v2, v3);
        *(uintx2*)(wptr + wbyte) = w;
    }
}

// ---------------------------------------------------------------------------
// Kernel A: 32(rows)x16(cols) output tile per block. NO min-waves clause:
// r10/r11 showed __launch_bounds__(256,4) makes the allocator split the
// unified file at accum_offset=64 (VGPR_Count=64) and spill ~30-47 MB to
// scratch. Unbounded, the allocator takes ~110 regs -> HW still fits
// 4 waves/EU (512/128 granule), zero spill (r8 precedent: 68 regs, 0.5 MB
// WRITE). conv1+relu (2x 16x16x32 MFMA) -> conv2+relu (32x32x16 MFMA,
// 9-shift) -> spatial sum -> atomicAdd feat_sum[B][32].
// ---------------------------------------------------------------------------
__global__ __launch_bounds__(256) void conv_feat_kernel(
    const float* __restrict__ x,      // (64,3,256,256)
    const void*  __restrict__ ws_ro,
    float* __restrict__ feat_sum)     // (64,32)
{
    __shared__ short s_in4[36 * 20 * 4];   // bf16 [r][col][c pad4] (5760 B)
    __shared__ short s_h1[2 * 4896];       // two ic-half planes 34x18 px (19584 B)
    __shared__ float s_part[4][32];

    const int t    = threadIdx.x;
    const int lane = t & 63, wv = t >> 6;
    const int q    = lane >> 4, ml = lane & 15;
    const int n32  = lane & 31, half = lane >> 5;
    const int tx = blockIdx.x, ty = blockIdx.y, b = blockIdx.z;
    const bool border = (tx == 0) | (tx == 15) | (ty == 0) | (ty == 7);

    // ---- conv1 weight fragments / bias only (B2 loaded after conv1) ----
    const short8* F = (const short8*)((const char*)ws_ro + WS_FRAG_OFF);
    short8 W1a = F[0 * 64 + lane];
    short8 W1b = F[1 * 64 + lane];
    floatx4 biasv = ((const floatx4*)((const char*)ws_ro + WS_BIAS1_OFF))[lane];

    // conv1 gather byte offsets (row stride 20 px * 8 B): positions q*2,q*2+1,8
    int lcB[3];
    {
        int p0 = q * 2, p1 = q * 2 + 1;
        lcB[0] = ((p0 / 3) * 20 + p0 % 3) * 8;
        lcB[1] = ((p1 / 3) * 20 + p1 % 3) * 8;
        lcB[2] = (2 * 20 + 2) * 8;
    }

    // ---- stage input tile as bf16 [r][col][4] (halo 2): 36 rows x 20 cols ----
    const int gy0 = ty * 32 - 2, gx0 = tx * 16 - 2;
    const float* xb = x + (size_t)b * 3 * 65536;
    if (!border) {
        for (int i = t; i < 720; i += 256) {
            int r = i / 20, c = i - r * 20;
            const float* p = xb + (gy0 + r) * 256 + gx0 + c;
            float v0 = p[0], v1 = p[65536], v2 = p[131072];
            uintx2 w; w.x = pk2(v0, v1); w.y = pk2(v2, 0.f);
            *(uintx2*)&s_in4[i * 4] = w;
        }
    } else {
        for (int i = t; i < 720; i += 256) {
            int r = i / 20, c = i - r * 20;
            int gy = gy0 + r, gx = gx0 + c;
            float v0 = 0.f, v1 = 0.f, v2 = 0.f;
            if ((unsigned)gy < 256u && (unsigned)gx < 256u) {
                const float* p = xb + gy * 256 + gx;
                v0 = p[0]; v1 = p[65536]; v2 = p[131072];
            }
            uintx2 w; w.x = pk2(v0, v1); w.y = pk2(v2, 0.f);
            *(uintx2*)&s_in4[i * 4] = w;
        }
    }
    __syncthreads();

    // ---- conv1 over 34x18 h1: 34 row-units + 4 col-units + corner ----
    char* wptr = (char*)s_h1 + (q >> 1) * PLANE_B + (q & 1) * 8;
    const char* inb = (const char*)s_in4;
    const int mlb = ml * 8;
    if (!border) {
#pragma unroll
        for (int i = 0; i < 8; ++i) {
            int u = wv * 8 + i;          // rows 0..31, cols 0..15
            conv1_tile(wptr, inb, lcB, u * 160 + mlb,
                       (u * 18 + ml) * 16, true, true, W1a, W1b, biasv);
        }
        if (wv < 2) {                    // rows 32,33
            int u = 32 + wv;
            conv1_tile(wptr, inb, lcB, u * 160 + mlb,
                       (u * 18 + ml) * 16, true, true, W1a, W1b, biasv);
        }
        {   // col unit: rows wv*8+(ml>>1), col 16+(ml&1)
            int rr = wv * 8 + (ml >> 1), cc = 16 + (ml & 1);
            conv1_tile(wptr, inb, lcB, rr * 160 + cc * 8,
                       (rr * 18 + cc) * 16, true, true, W1a, W1b, biasv);
        }
        if (wv == 2) {   // corner 4 px: rows 32-33 x cols 16-17
            int ml2 = ml & 3;
            int iy = 32 + (ml2 >> 1), ix = 16 + (ml2 & 1);
            conv1_tile(wptr, inb, lcB, iy * 160 + ix * 8,
                       (iy * 18 + ix) * 16, true, ml < 4, W1a, W1b, biasv);
        }
    } else {
        const bool gxOK = (unsigned)(tx * 16 - 1 + ml) < 256u;
#pragma unroll
        for (int i = 0; i < 8; ++i) {
            int u = wv * 8 + i;
            bool ok = ((unsigned)(ty * 32 - 1 + u) < 256u) & gxOK;
            conv1_tile(wptr, inb, lcB, u * 160 + mlb,
                       (u * 18 + ml) * 16, ok, true, W1a, W1b, biasv);
        }
        if (wv < 2) {
            int u = 32 + wv;
            bool ok = ((unsigned)(ty * 32 - 1 + u) < 256u) & gxOK;
            conv1_tile(wptr, inb, lcB, u * 160 + mlb,
                       (u * 18 + ml) * 16, ok, true, W1a, W1b, biasv);
        }
        {
            int rr = wv * 8 + (ml >> 1), cc = 16 + (ml & 1);
            bool ok = ((unsigned)(ty * 32 - 1 + rr) < 256u) &
                      ((unsigned)(tx * 16 - 1 + cc) < 256u);
            conv1_tile(wptr, inb, lcB, rr * 160 + cc * 8,
                       (rr * 18 + cc) * 16, ok, true, W1a, W1b, biasv);
        }
        if (wv == 2) {
            int ml2 = ml & 3;
            int iy = 32 + (ml2 >> 1), ix = 16 + (ml2 & 1);
            bool ok = ((unsigned)(ty * 32 - 1 + iy) < 256u) &
                      ((unsigned)(tx * 16 - 1 + ix) < 256u);
            conv1_tile(wptr, inb, lcB, iy * 160 + ix * 8,
                       (iy * 18 + ix) * 16, ok, ml < 4, W1a, W1b, biasv);
        }
    }
    __syncthreads();

    // ---- conv2: B2 loaded here (post-conv1); wave = 4x 32-px tiles
    //      (2 rows x 16 cols), rows wv*8..wv*8+7; A-frags loaded per ky ----
    short8 B2[9];
#pragma unroll
    for (int s = 0; s < 9; ++s) B2[s] = F[(2 + s) * 64 + lane];
    float b2v = ((const float*)((const char*)ws_ro + WS_BIAS2_OFF))[lane];

    float part = 0.0f;
    {
        const int prow0 = n32 >> 4, pcol = n32 & 15;
        const char* pl = (const char*)s_h1 + half * PLANE_B;
#pragma unroll
        for (int it = 0; it < 4; ++it) {
            const int pb = ((wv * 8 + 2 * it + prow0) * 18 + pcol) * 16;
            floatx16 acc;
#pragma unroll
            for (int r = 0; r < 16; ++r) acc[r] = b2v;
#pragma unroll
            for (int ky = 0; ky < 3; ++ky) {
                const char* rp = pl + pb + ky * 288;   // 18 px * 16 B
                short8 A0 = *(const short8*)(rp);
                short8 A1 = *(const short8*)(rp + 16);
                short8 A2 = *(const short8*)(rp + 32);
                acc = __builtin_amdgcn_mfma_f32_32x32x16_bf16(A0, B2[ky * 3 + 0], acc, 0, 0, 0);
                acc = __builtin_amdgcn_mfma_f32_32x32x16_bf16(A1, B2[ky * 3 + 1], acc, 0, 0, 0);
                acc = __builtin_amdgcn_mfma_f32_32x32x16_bf16(A2, B2[ky * 3 + 2], acc, 0, 0, 0);
            }
#pragma unroll
            for (int r = 0; r < 16; ++r) part += fmaxf(acc[r], 0.0f);
        }
    }
    part += __shfl_xor(part, 32);
    if (lane < 32) s_part[wv][n32] = part;
    __syncthreads();
    if (t < 32) {
        float ssum = s_part[0][t] + s_part[1][t] + s_part[2][t] + s_part[3][t];
        atomicAdd(feat_sum + b * 32 + t, ssum);
    }
}

// ---------------------------------------------------------------------------
// Kernel B: gating. One block per batch row, 64 threads (= experts, 1 wave).
// ---------------------------------------------------------------------------
__global__ __launch_bounds__(64) void router_gate_kernel(
    const int* __restrict__ task_id,
    const float* __restrict__ noise,
    const float* __restrict__ mlp_w1,
    const float* __restrict__ mlp_b1,
    const float* __restrict__ mlp_w2,
    const float* __restrict__ mlp_b2,
    const float* __restrict__ deg_w,
    const float* __restrict__ deg_b,
    const float* __restrict__ keys,
    const float* __restrict__ gate_w,
    const float* __restrict__ gate_b,
    const float* __restrict__ noise_w,
    const float* __restrict__ noise_b,
    const float* __restrict__ feat_sum,
    float* __restrict__ out)
{
    const int b = blockIdx.x;
    const int e = threadIdx.x;

    __shared__ float s_te[32];
    __shared__ float s_comb[32];
    __shared__ float s_ew[64];

    if (e < 32) {
        float tf = (float)task_id[b];
        s_te[e] = fmaxf(tf * mlp_w1[e] + mlp_b1[e], 0.0f);
    }
    __syncthreads();
    if (e < 32) {
        float acc = mlp_b2[e];
        for (int k = 0; k < 32; ++k) acc += s_te[k] * mlp_w2[k * 32 + e];
        float dacc = deg_b[e];
        for (int c = 0; c < 32; ++c)
            dacc += (feat_sum[b * 32 + c] * (1.0f / 65536.0f)) * deg_w[c * 32 + e];
        s_comb[e] = acc + 0.2f * dacc;  // ALPHA = 0.8
    }
    __syncthreads();

    float s = 0.0f;
    for (int d = 0; d < 32; ++d) s += s_comb[d] * keys[e * 32 + d];
    s *= 0.17677669529663687f;  // 1/sqrt(32)

    float m = s;
    for (int off = 32; off; off >>= 1) m = fmaxf(m, __shfl_xor(m, off));
    float p = expf(s - m);
    float sum = p;
    for (int off = 32; off; off >>= 1) sum += __shfl_xor(sum, off);
    float w = p / sum;
    s_ew[e] = w;
    __syncthreads();

    float cl = gate_b[e], nz = noise_b[e];
    for (int k = 0; k < 64; ++k) {
        float ewk = s_ew[k];
        cl += ewk * gate_w[k * 64 + e];
        nz += ewk * noise_w[k * 64 + e];
    }
    float sp = (nz > 20.0f) ? nz : log1pf(expf(nz));
    float logit = cl + noise[b * 64 + e] * (sp + 0.01f);

    float v0 = logit; int i0 = e;
    for (int off = 32; off; off >>= 1) {
        float ov = __shfl_xor(v0, off);
        int   oi = __shfl_xor(i0, off);
        if (ov > v0 || (ov == v0 && oi < i0)) { v0 = ov; i0 = oi; }
    }
    float v1 = (e == i0) ? -INFINITY : logit; int i1 = e;
    for (int off = 32; off; off >>= 1) {
        float ov = __shfl_xor(v1, off);
        int   oi = __shfl_xor(i1, off);
        if (ov > v1 || (ov == v1 && oi < i1)) { v1 = ov; i1 = oi; }
    }

    float e1 = expf(v1 - v0);
    float g0 = 1.0f / (1.0f + e1);
    float g1 = e1 / (1.0f + e1);

    float g = (e == i0) ? g0 : (e == i1) ? g1 : 0.0f;
    out[b * 64 + e] = g;
    if (g != 0.0f) atomicAdd(out + 64 * 64 + e, g);
}

extern "C" void kernel_launch(void* const* d_in, const int* in_sizes, int n_in,
                              void* d_out, int out_size, void* d_ws, size_t ws_size,
                              hipStream_t stream) {
    const int*   task_id = (const int*)d_in[0];
    const float* x       = (const float*)d_in[1];
    const float* noise   = (const float*)d_in[2];
    const float* mlp_w1  = (const float*)d_in[3];
    const float* mlp_b1  = (const float*)d_in[4];
    const float* mlp_w2  = (const float*)d_in[5];
    const float* mlp_b2  = (const float*)d_in[6];
    const float* conv1_w = (const float*)d_in[7];
    const float* conv1_b = (const float*)d_in[8];
    const float* conv2_w = (const float*)d_in[9];
    const float* conv2_b = (const float*)d_in[10];
    const float* deg_w   = (const float*)d_in[11];
    const float* deg_b   = (const float*)d_in[12];
    const float* keys    = (const float*)d_in[13];
    const float* gate_w  = (const float*)d_in[14];
    const float* gate_b  = (const float*)d_in[15];
    const float* noise_w = (const float*)d_in[16];
    const float* noise_b = (const float*)d_in[17];

    float* out  = (float*)d_out;
    float* feat = (float*)d_ws;

    build_frags_kernel<<<1, 256, 0, stream>>>(conv1_w, conv1_b, conv2_w,
                                              conv2_b, d_ws, out);
    dim3 gridA(16, 8, 64);
    conv_feat_kernel<<<gridA, 256, 0, stream>>>(x, d_ws, feat);
    router_gate_kernel<<<64, 64, 0, stream>>>(
        task_id, noise, mlp_w1, mlp_b1, mlp_w2, mlp_b2, deg_w, deg_b, keys,
        gate_w, gate_b, noise_w, noise_b, feat, out);
}